// Round 12
// baseline (171.489 us; speedup 1.0000x reference)
//
#include <hip/hip_runtime.h>
#include <hip/hip_bf16.h>
#include <math.h>
#include <stdint.h>

#define Bq 4
#define Sq 2048
#define DMq 1024
#define Hq 16
#define Dq 64
#define CAPf 15.0f
#define EPSf 1e-6f
#define Tc 64
#define Cc (Sq / Tc)         // 32 chunks
#define QKVW (3 * Hq * Dq)   // 3072
#define NGATE (3 * Hq)       // 48
#define NPAD 3200            // wcomb rows (rows 3072..3119 = w_gate, rest 0)
#define MSc (Bq * Sq)        // 8192

typedef __attribute__((ext_vector_type(8))) short short8;
typedef __attribute__((ext_vector_type(4))) float f32x4;
typedef __hip_bfloat16 bf16;

__device__ __forceinline__ float b2f(bf16 v) { return __bfloat162float(v); }
__device__ __forceinline__ bf16  f2b(float v) { return __float2bfloat16(v); }
__device__ __forceinline__ uint16_t f2bu(float f) {
    bf16 h = __float2bfloat16(f); uint16_t u; __builtin_memcpy(&u, &h, 2); return u;
}
__device__ __forceinline__ float bu2f(uint16_t u) {
    uint32_t x = ((uint32_t)u) << 16; float f; __builtin_memcpy(&f, &x, 4); return f;
}
// gate = sigmoid(CAP * tanh(v / CAP)) via v_exp_f32 only.
__device__ __forceinline__ float gate_act(float v) {
    float t = v * (1.0f / CAPf);
    float e2 = __expf(2.0f * t);
    float th = 1.0f - 2.0f / (e2 + 1.0f);
    return 1.0f / (1.0f + __expf(-CAPf * th));
}

// ---------------- prep: rmsnorm (blocks 0..MS-1) + weight converts (rest) ----------------
__global__ void prep_kernel(const float* __restrict__ x,
                            const float* __restrict__ ln_w,
                            const float* __restrict__ wqkv,
                            const float* __restrict__ wgate,
                            const float* __restrict__ wout,
                            bf16* __restrict__ xn,
                            bf16* __restrict__ wcomb, bf16* __restrict__ wob) {
    int tid = threadIdx.x;
    if (blockIdx.x < MSc) {
        int row = blockIdx.x;
        const float4* xr = (const float4*)(x + (size_t)row * DMq);
        float4 v = xr[tid];
        float ss = v.x*v.x + v.y*v.y + v.z*v.z + v.w*v.w;
        #pragma unroll
        for (int off = 32; off > 0; off >>= 1) ss += __shfl_down(ss, off);
        __shared__ float red[4];
        int lane = tid & 63, wv = tid >> 6;
        if (lane == 0) red[wv] = ss;
        __syncthreads();
        float tot = red[0] + red[1] + red[2] + red[3];
        float rs = rsqrtf(tot * (1.0f / DMq) + EPSf);
        float4 w4 = ((const float4*)ln_w)[tid];
        bf16 t[4] = {f2b(v.x * rs * w4.x), f2b(v.y * rs * w4.y),
                     f2b(v.z * rs * w4.z), f2b(v.w * rs * w4.w)};
        *(uint2*)(xn + (size_t)row * DMq + tid * 4) = *(uint2*)t;
        return;
    }
    const int n1 = QKVW * DMq / 4;               // 786432
    const int n2 = (NPAD - QKVW) * DMq / 4;      // 32768
    const int ng = NGATE * DMq / 4;              // 12288
    const int n3 = DMq * Hq * Dq / 4;            // 262144
    int i = (blockIdx.x - MSc) * 256 + tid;
    if (i < n1) {
        float4 v = ((const float4*)wqkv)[i];
        bf16 t[4] = {f2b(v.x), f2b(v.y), f2b(v.z), f2b(v.w)};
        ((uint2*)wcomb)[i] = *(uint2*)t;
    } else if (i < n1 + n2) {
        int j = i - n1;
        uint2 o = make_uint2(0u, 0u);
        if (j < ng) {
            float4 v = ((const float4*)wgate)[j];
            bf16 t[4] = {f2b(v.x), f2b(v.y), f2b(v.z), f2b(v.w)};
            o = *(uint2*)t;
        }
        ((uint2*)wcomb)[n1 + j] = o;
    } else if (i < n1 + n2 + n3) {
        int j = i - n1 - n2;
        float4 v = ((const float4*)wout)[j];
        bf16 t[4] = {f2b(v.x), f2b(v.y), f2b(v.z), f2b(v.w)};
        ((uint2*)wob)[j] = *(uint2*)t;
    }
}

// ---------------- QKV GEMM: pure 128x128 m97 structure (== proven r4 kernel) ----------------
// NO xcd swizzle: working set is L3-resident; r11 A/B showed swizzle costs 13%
// here (67 vs 59 us, VALUBusy 2x, VGPR +8). Natural round-robin order wins.
__global__ __launch_bounds__(256) void gemm_qkv(const bf16* __restrict__ A,
                                                const bf16* __restrict__ Bw,
                                                bf16* __restrict__ qkvb,
                                                int M, int N, int K) {
    __shared__ bf16 As[128 * 64];
    __shared__ bf16 Bs[128 * 64];
    const int tid = threadIdx.x;
    const int w = tid >> 6;
    const int l = tid & 63;
    const int wr = (w >> 1) * 64;
    const int wc = (w & 1) * 64;
    const int bm = blockIdx.y * 128;
    const int bn = blockIdx.x * 128;

    const int lrow = l >> 3;
    const int swzc = ((l & 7) ^ lrow) * 8;
    const int fl = l & 15;
    const int kb = l >> 4;
    const int rsw = l & 7;

    f32x4 acc[4][4];
    #pragma unroll
    for (int i = 0; i < 4; i++)
        #pragma unroll
        for (int j = 0; j < 4; j++) acc[i][j] = (f32x4){0.f, 0.f, 0.f, 0.f};

    for (int k0 = 0; k0 < K; k0 += 64) {
        __syncthreads();
        #pragma unroll
        for (int inst = 0; inst < 4; inst++) {
            int r0 = w * 32 + inst * 8;
            const bf16* gp = A + (size_t)(bm + r0 + lrow) * K + k0 + swzc;
            __builtin_amdgcn_global_load_lds(
                (const __attribute__((address_space(1))) uint32_t*)gp,
                (__attribute__((address_space(3))) uint32_t*)(As + r0 * 64),
                16, 0, 0);
        }
        #pragma unroll
        for (int inst = 0; inst < 4; inst++) {
            int r0 = w * 32 + inst * 8;
            const bf16* gp = Bw + (size_t)(bn + r0 + lrow) * K + k0 + swzc;
            __builtin_amdgcn_global_load_lds(
                (const __attribute__((address_space(1))) uint32_t*)gp,
                (__attribute__((address_space(3))) uint32_t*)(Bs + r0 * 64),
                16, 0, 0);
        }
        __syncthreads();
        #pragma unroll
        for (int kk2 = 0; kk2 < 2; kk2++) {
            const int koff = (((kk2 << 2) + kb) ^ rsw) * 8;
            short8 af[4], bfr[4];
            #pragma unroll
            for (int i = 0; i < 4; i++)
                af[i] = *(const short8*)(As + (wr + i * 16 + fl) * 64 + koff);
            #pragma unroll
            for (int j = 0; j < 4; j++)
                bfr[j] = *(const short8*)(Bs + (wc + j * 16 + fl) * 64 + koff);
            #pragma unroll
            for (int i = 0; i < 4; i++)
                #pragma unroll
                for (int j = 0; j < 4; j++)
                    acc[i][j] = __builtin_amdgcn_mfma_f32_16x16x32_bf16(
                        af[i], bfr[j], acc[i][j], 0, 0, 0);
        }
    }

    #pragma unroll
    for (int i = 0; i < 4; i++) {
        #pragma unroll
        for (int j = 0; j < 4; j++) {
            int col = bn + wc + j * 16 + fl;
            #pragma unroll
            for (int r = 0; r < 4; r++) {
                int row = bm + wr + i * 16 + kb * 4 + r;
                qkvb[(size_t)row * N + col] = f2b(acc[i][j][r]);
            }
        }
    }
}

// ---------------- skinny gates GEMM: 32 rows x 48 cols per block, 1 wave ----------------
__global__ __launch_bounds__(64) void gemm_gates(const bf16* __restrict__ A,
                                                 const bf16* __restrict__ Bw,
                                                 float* __restrict__ gates_t,
                                                 int M, int K) {
    const int bm = blockIdx.x * 32;
    const int l = threadIdx.x, fl = l & 15, kb = l >> 4;
    f32x4 acc[2][3];
    #pragma unroll
    for (int i = 0; i < 2; i++)
        #pragma unroll
        for (int j = 0; j < 3; j++) acc[i][j] = (f32x4){0.f, 0.f, 0.f, 0.f};

    for (int ks = 0; ks < K; ks += 32) {
        short8 af[2], bf[3];
        #pragma unroll
        for (int i = 0; i < 2; i++)
            af[i] = *(const short8*)(A + (size_t)(bm + i * 16 + fl) * K + ks + kb * 8);
        #pragma unroll
        for (int j = 0; j < 3; j++)
            bf[j] = *(const short8*)(Bw + (size_t)(j * 16 + fl) * K + ks + kb * 8);
        #pragma unroll
        for (int i = 0; i < 2; i++)
            #pragma unroll
            for (int j = 0; j < 3; j++)
                acc[i][j] = __builtin_amdgcn_mfma_f32_16x16x32_bf16(af[i], bf[j], acc[i][j], 0, 0, 0);
    }
    #pragma unroll
    for (int i = 0; i < 2; i++)
        #pragma unroll
        for (int j = 0; j < 3; j++)
            #pragma unroll
            for (int r = 0; r < 4; r++) {
                int row = bm + i * 16 + kb * 4 + r;
                int g = j * 16 + fl;
                gates_t[(size_t)g * M + row] = gate_act(acc[i][j][r]);
            }
}

// ---------------- out GEMM (pure 128x128 m97 structure) ----------------
__global__ __launch_bounds__(256) void gemm_out(const bf16* __restrict__ A,
                                                const bf16* __restrict__ Bw,
                                                const float* __restrict__ resid,
                                                float* __restrict__ C,
                                                int M, int N, int K) {
    __shared__ bf16 As[128 * 64];
    __shared__ bf16 Bs[128 * 64];
    const int tid = threadIdx.x;
    const int w = tid >> 6;
    const int l = tid & 63;
    const int wr = (w >> 1) * 64;
    const int wc = (w & 1) * 64;
    const int bm = blockIdx.y * 128;
    const int bn = blockIdx.x * 128;

    const int lrow = l >> 3;
    const int swzc = ((l & 7) ^ lrow) * 8;
    const int fl = l & 15;
    const int kb = l >> 4;
    const int rsw = l & 7;

    f32x4 acc[4][4];
    #pragma unroll
    for (int i = 0; i < 4; i++)
        #pragma unroll
        for (int j = 0; j < 4; j++) acc[i][j] = (f32x4){0.f, 0.f, 0.f, 0.f};

    for (int k0 = 0; k0 < K; k0 += 64) {
        __syncthreads();
        #pragma unroll
        for (int inst = 0; inst < 4; inst++) {
            int r0 = w * 32 + inst * 8;
            const bf16* gp = A + (size_t)(bm + r0 + lrow) * K + k0 + swzc;
            __builtin_amdgcn_global_load_lds(
                (const __attribute__((address_space(1))) uint32_t*)gp,
                (__attribute__((address_space(3))) uint32_t*)(As + r0 * 64),
                16, 0, 0);
        }
        #pragma unroll
        for (int inst = 0; inst < 4; inst++) {
            int r0 = w * 32 + inst * 8;
            const bf16* gp = Bw + (size_t)(bn + r0 + lrow) * K + k0 + swzc;
            __builtin_amdgcn_global_load_lds(
                (const __attribute__((address_space(1))) uint32_t*)gp,
                (__attribute__((address_space(3))) uint32_t*)(Bs + r0 * 64),
                16, 0, 0);
        }
        __syncthreads();
        #pragma unroll
        for (int kk2 = 0; kk2 < 2; kk2++) {
            const int koff = (((kk2 << 2) + kb) ^ rsw) * 8;
            short8 af[4], bfr[4];
            #pragma unroll
            for (int i = 0; i < 4; i++)
                af[i] = *(const short8*)(As + (wr + i * 16 + fl) * 64 + koff);
            #pragma unroll
            for (int j = 0; j < 4; j++)
                bfr[j] = *(const short8*)(Bs + (wc + j * 16 + fl) * 64 + koff);
            #pragma unroll
            for (int i = 0; i < 4; i++)
                #pragma unroll
                for (int j = 0; j < 4; j++)
                    acc[i][j] = __builtin_amdgcn_mfma_f32_16x16x32_bf16(
                        af[i], bfr[j], acc[i][j], 0, 0, 0);
        }
    }

    #pragma unroll
    for (int i = 0; i < 4; i++) {
        #pragma unroll
        for (int j = 0; j < 4; j++) {
            int col = bn + wc + j * 16 + fl;
            #pragma unroll
            for (int r = 0; r < 4; r++) {
                int row = bm + wr + i * 16 + kb * 4 + r;
                size_t idx = (size_t)row * N + col;
                C[idx] = acc[i][j][r] + resid[idx];
            }
        }
    }
}

// ---------------- chunk kernel A: intra-chunk attention + chunk state ----------------
__global__ __launch_bounds__(64) void chunk_intra(const bf16* __restrict__ qkvb,
                                                  const float* __restrict__ gates,
                                                  bf16* __restrict__ attb,
                                                  bf16* __restrict__ LT,
                                                  float* __restrict__ oaArr,
                                                  float* __restrict__ Fch) {
    const int blk = blockIdx.x;
    const int c  = blk & (Cc - 1);
    const int bh = blk >> 5;
    const int b = bh >> 4, hh = bh & 15;
    const int l = threadIdx.x;
    const int s0 = c * Tc;

    __shared__ bf16 KTs[4096];
    __shared__ bf16 VTs[4096];
    __shared__ bf16 Ps[4096];
    __shared__ float rowS[64], pcolS[64], wstS[64];

    // gates in [48][MS] layout -> coalesced 64-lane reads
    const int rix = b * Sq + s0 + l;
    float ig = gates[(size_t)(0 * Hq + hh) * MSc + rix];
    float fg = gates[(size_t)(1 * Hq + hh) * MSc + rix];
    float og = gates[(size_t)(2 * Hq + hh) * MSc + rix];
    float la = __logf(fg);
    #pragma unroll
    for (int off = 1; off < 64; off <<= 1) {
        float v = __shfl_up(la, off);
        if (l >= off) la += v;
    }
    float la63 = __shfl(la, 63);
    float li = __logf(ig);
    rowS[l]  = la + __logf(og);
    pcolS[l] = li - la;
    wstS[l]  = __expf(la63 - la + li);
    float oa = og * __expf(la);
    oaArr[(size_t)blk * 64 + l] = oa;
    if (l == 0) Fch[blk] = __expf(la63);
    __syncthreads();

    const int cg = l & 7, rp = l >> 3;
    const size_t rowBase = (size_t)(b * Sq + s0);
    const int kcol = (Hq + hh) * Dq, vcol = (2 * Hq + hh) * Dq;
    #pragma unroll
    for (int pass = 0; pass < 4; pass++) {
        int j0 = pass * 16 + rp * 2;
        const bf16* r0 = qkvb + (rowBase + j0) * QKVW;
        const bf16* r1 = qkvb + (rowBase + j0 + 1) * QKVW;
        short8 k0 = *(const short8*)(r0 + kcol + cg * 8);
        short8 k1 = *(const short8*)(r1 + kcol + cg * 8);
        short8 v0 = *(const short8*)(r0 + vcol + cg * 8);
        short8 v1 = *(const short8*)(r1 + vcol + cg * 8);
        float w0 = wstS[j0], w1 = wstS[j0 + 1];
        #pragma unroll
        for (int s = 0; s < 8; s++) {
            int cc = cg * 8 + s;
            int base = cc * 64 + ((((j0 >> 3) ^ (cc & 7) ^ (cc >> 3))) << 3) + (j0 & 7);
            uint32_t kp = (uint32_t)f2bu(bu2f((uint16_t)k0[s]) * w0)
                        | ((uint32_t)f2bu(bu2f((uint16_t)k1[s]) * w1) << 16);
            uint32_t vp = (uint32_t)(uint16_t)v0[s] | ((uint32_t)(uint16_t)v1[s] << 16);
            *(uint32_t*)&KTs[base] = kp;
            *(uint32_t*)&VTs[base] = vp;
        }
    }

    const int fl = l & 15, kb = l >> 4;
    const bf16* Qb = qkvb + rowBase * QKVW + hh * Dq;
    const bf16* Kb = qkvb + rowBase * QKVW + kcol;
    f32x4 accS[4][4];
    #pragma unroll
    for (int i = 0; i < 4; i++)
        #pragma unroll
        for (int j = 0; j < 4; j++) accS[i][j] = (f32x4){0.f, 0.f, 0.f, 0.f};
    #pragma unroll
    for (int ks = 0; ks < 2; ks++) {
        short8 qf[4], kf[4];
        #pragma unroll
        for (int i = 0; i < 4; i++)
            qf[i] = *(const short8*)(Qb + (size_t)(i * 16 + fl) * QKVW + ks * 32 + kb * 8);
        #pragma unroll
        for (int j = 0; j < 4; j++)
            kf[j] = *(const short8*)(Kb + (size_t)(j * 16 + fl) * QKVW + ks * 32 + kb * 8);
        #pragma unroll
        for (int i = 0; i < 4; i++)
            #pragma unroll
            for (int j = 0; j < 4; j++)
                accS[i][j] = __builtin_amdgcn_mfma_f32_16x16x32_bf16(qf[i], kf[j], accS[i][j], 0, 0, 0);
    }

    #pragma unroll
    for (int i = 0; i < 4; i++) {
        #pragma unroll
        for (int j = 0; j < 4; j++) {
            int jj = j * 16 + fl;
            float pc = pcolS[jj];
            #pragma unroll
            for (int r = 0; r < 4; r++) {
                int t = i * 16 + kb * 4 + r;
                float p = (jj <= t) ? __expf(rowS[t] + pc) * accS[i][j][r] : 0.f;
                int slot = (jj >> 3) ^ (t & 7) ^ (t >> 3);
                Ps[t * 64 + slot * 8 + (jj & 7)] = f2b(p);
            }
        }
    }
    __syncthreads();

    f32x4 accO[4][4], accL[4][4];
    #pragma unroll
    for (int i = 0; i < 4; i++)
        #pragma unroll
        for (int j = 0; j < 4; j++) {
            accO[i][j] = (f32x4){0.f, 0.f, 0.f, 0.f};
            accL[i][j] = (f32x4){0.f, 0.f, 0.f, 0.f};
        }
    #pragma unroll
    for (int ks = 0; ks < 2; ks++) {
        short8 pf[4], vt[4], kt[4];
        #pragma unroll
        for (int i = 0; i < 4; i++) {
            int row = i * 16 + fl;
            int koff = (((ks * 4 + kb) ^ (row & 7) ^ (row >> 3))) << 3;
            pf[i] = *(const short8*)(Ps  + row * 64 + koff);
            vt[i] = *(const short8*)(VTs + row * 64 + koff);
            kt[i] = *(const short8*)(KTs + row * 64 + koff);
        }
        #pragma unroll
        for (int i = 0; i < 4; i++)
            #pragma unroll
            for (int j = 0; j < 4; j++) {
                accO[i][j] = __builtin_amdgcn_mfma_f32_16x16x32_bf16(pf[i], vt[j], accO[i][j], 0, 0, 0);
                accL[i][j] = __builtin_amdgcn_mfma_f32_16x16x32_bf16(vt[i], kt[j], accL[i][j], 0, 0, 0);
            }
    }

    #pragma unroll
    for (int i = 0; i < 4; i++)
        #pragma unroll
        for (int j = 0; j < 4; j++)
            #pragma unroll
            for (int r = 0; r < 4; r++) {
                int rr = i * 16 + kb * 4 + r, cc2 = j * 16 + fl;
                attb[(rowBase + rr) * (Hq * Dq) + hh * Dq + cc2] = f2b(accO[i][j][r]);
                LT[(size_t)blk * 4096 + rr * 64 + cc2] = f2b(accL[i][j][r]);
            }
}

// ---------------- pass2: cross-chunk combine ----------------
__global__ __launch_bounds__(256) void scan_pass2(bf16* __restrict__ LH,
                                                  const float* __restrict__ Fchunk,
                                                  const float* __restrict__ h0,
                                                  float* __restrict__ hfin) {
    int idx = blockIdx.x * 256 + threadIdx.x;
    int bh = idx >> 12;
    int ed = idx & 4095;
    int e = ed >> 6, d = ed & 63;
    float run = h0[(size_t)bh * 4096 + d * 64 + e];
    #pragma unroll
    for (int c = 0; c < Cc; c++) {
        float Fv = Fchunk[bh * Cc + c];
        size_t off = ((size_t)bh * Cc + c) * 4096 + ed;
        float Lv = b2f(LH[off]);
        LH[off] = f2b(run);
        run = Fv * run + Lv;
    }
    hfin[(size_t)bh * 4096 + d * 64 + e] = run;
}

// ---------------- chunk kernel B: cross-chunk contribution ----------------
__global__ __launch_bounds__(64) void chunk_cross(const bf16* __restrict__ qkvb,
                                                  const bf16* __restrict__ HT,
                                                  const float* __restrict__ oaArr,
                                                  bf16* __restrict__ attb) {
    const int blk = blockIdx.x;
    const int c = blk & (Cc - 1);
    const int bh = blk >> 5;
    const int b = bh >> 4, hh = bh & 15;
    const int l = threadIdx.x, fl = l & 15, kb = l >> 4;
    const size_t rowBase = (size_t)(b * Sq + c * Tc);
    __shared__ float oaS[64];
    oaS[l] = oaArr[(size_t)blk * 64 + l];
    __syncthreads();
    const bf16* Qb = qkvb + rowBase * QKVW + hh * Dq;
    const bf16* Hb = HT + (size_t)blk * 4096;
    f32x4 acc[4][4];
    #pragma unroll
    for (int i = 0; i < 4; i++)
        #pragma unroll
        for (int j = 0; j < 4; j++) acc[i][j] = (f32x4){0.f, 0.f, 0.f, 0.f};
    #pragma unroll
    for (int ks = 0; ks < 2; ks++) {
        short8 qf[4], hf[4];
        #pragma unroll
        for (int i = 0; i < 4; i++)
            qf[i] = *(const short8*)(Qb + (size_t)(i * 16 + fl) * QKVW + ks * 32 + kb * 8);
        #pragma unroll
        for (int j = 0; j < 4; j++)
            hf[j] = *(const short8*)(Hb + (j * 16 + fl) * 64 + ks * 32 + kb * 8);
        #pragma unroll
        for (int i = 0; i < 4; i++)
            #pragma unroll
            for (int j = 0; j < 4; j++)
                acc[i][j] = __builtin_amdgcn_mfma_f32_16x16x32_bf16(qf[i], hf[j], acc[i][j], 0, 0, 0);
    }
    #pragma unroll
    for (int i = 0; i < 4; i++)
        #pragma unroll
        for (int j = 0; j < 4; j++)
            #pragma unroll
            for (int r = 0; r < 4; r++) {
                int t = i * 16 + kb * 4 + r, e = j * 16 + fl;
                size_t idx = (rowBase + t) * (Hq * Dq) + hh * Dq + e;
                attb[idx] = f2b(b2f(attb[idx]) + oaS[t] * acc[i][j][r]);
            }
}

extern "C" void kernel_launch(void* const* d_in, const int* in_sizes, int n_in,
                              void* d_out, int out_size, void* d_ws, size_t ws_size,
                              hipStream_t stream) {
    const float* x      = (const float*)d_in[0];
    const float* h0     = (const float*)d_in[1];
    const float* w_qkv  = (const float*)d_in[2];
    const float* w_gate = (const float*)d_in[3];
    const float* w_out  = (const float*)d_in[4];
    const float* ln_w   = (const float*)d_in[5];

    const size_t MS = (size_t)Bq * Sq;            // 8192
    const size_t BH = (size_t)Bq * Hq;            // 64

    float* p = (float*)d_ws;
    bf16*  xnb   = (bf16*)p;  p += MS * DMq / 2;
    bf16*  qkvb  = (bf16*)p;  p += MS * QKVW / 2;
    float* gates = p;         p += MS * NGATE;            // layout [48][MS]
    float* oaArr = p;         p += BH * Cc * Tc;
    float* Fch   = p;         p += BH * Cc;
    bf16*  LT    = (bf16*)p;  p += BH * Cc * Dq * Dq / 2;
    bf16*  wcomb = (bf16*)p;  p += (size_t)NPAD * DMq / 2;
    bf16*  wob   = (bf16*)p;  p += (size_t)DMq * Hq * Dq / 2;
    size_t need = (size_t)(p - (float*)d_ws) * sizeof(float);
    if (ws_size < need) return;
    bf16* attb = xnb;   // alias: xnb dead after QKV+gates GEMMs

    float* y    = (float*)d_out;
    float* hfin = y + MS * DMq;

    const int cvt_n = (QKVW * DMq + (NPAD - QKVW) * DMq + DMq * Hq * Dq) / 4;
    const int cvt_blocks = (cvt_n + 255) / 256;
    prep_kernel<<<dim3(MS + cvt_blocks), dim3(256), 0, stream>>>(
        x, ln_w, w_qkv, w_gate, w_out, xnb, wcomb, wob);

    gemm_qkv<<<dim3(QKVW / 128, MS / 128), dim3(256), 0, stream>>>(
        xnb, wcomb, qkvb, (int)MS, QKVW, DMq);

    gemm_gates<<<dim3(MS / 32), dim3(64), 0, stream>>>(
        xnb, wcomb + (size_t)QKVW * DMq, gates, (int)MS, DMq);

    chunk_intra<<<dim3(BH * Cc), dim3(64), 0, stream>>>(qkvb, gates, attb, LT, oaArr, Fch);
    scan_pass2<<<dim3(BH * 4096 / 256), dim3(256), 0, stream>>>(LT, Fch, h0, hfin);
    chunk_cross<<<dim3(BH * Cc), dim3(64), 0, stream>>>(qkvb, LT, oaArr, attb);

    gemm_out<<<dim3(DMq / 128, MS / 128), dim3(256), 0, stream>>>(
        attb, wob, x, y, (int)MS, DMq, Hq * Dq);
}

// Round 13
// 160.105 us; speedup vs baseline: 1.0711x; 1.0711x over previous
//
#include <hip/hip_runtime.h>
#include <hip/hip_bf16.h>
#include <math.h>
#include <stdint.h>

#define Bq 4
#define Sq 2048
#define DMq 1024
#define Hq 16
#define Dq 64
#define CAPf 15.0f
#define EPSf 1e-6f
#define Tc 64
#define Cc (Sq / Tc)         // 32 chunks
#define QKVW (3 * Hq * Dq)   // 3072
#define NGATE (3 * Hq)       // 48
#define NPAD 3200            // wcomb rows (rows 3072..3119 = w_gate, rest 0)
#define MSc (Bq * Sq)        // 8192

typedef __attribute__((ext_vector_type(8))) short short8;
typedef __attribute__((ext_vector_type(4))) float f32x4;
typedef __hip_bfloat16 bf16;

__device__ __forceinline__ float b2f(bf16 v) { return __bfloat162float(v); }
__device__ __forceinline__ bf16  f2b(float v) { return __float2bfloat16(v); }
__device__ __forceinline__ uint16_t f2bu(float f) {
    bf16 h = __float2bfloat16(f); uint16_t u; __builtin_memcpy(&u, &h, 2); return u;
}
__device__ __forceinline__ float bu2f(uint16_t u) {
    uint32_t x = ((uint32_t)u) << 16; float f; __builtin_memcpy(&f, &x, 4); return f;
}
// gate = sigmoid(CAP * tanh(v / CAP)) via v_exp_f32 only.
__device__ __forceinline__ float gate_act(float v) {
    float t = v * (1.0f / CAPf);
    float e2 = __expf(2.0f * t);
    float th = 1.0f - 2.0f / (e2 + 1.0f);
    return 1.0f / (1.0f + __expf(-CAPf * th));
}

// ---------------- prep: rmsnorm (blocks 0..MS-1) + weight converts (rest) ----------------
__global__ void prep_kernel(const float* __restrict__ x,
                            const float* __restrict__ ln_w,
                            const float* __restrict__ wqkv,
                            const float* __restrict__ wgate,
                            const float* __restrict__ wout,
                            bf16* __restrict__ xn,
                            bf16* __restrict__ wcomb, bf16* __restrict__ wob) {
    int tid = threadIdx.x;
    if (blockIdx.x < MSc) {
        int row = blockIdx.x;
        const float4* xr = (const float4*)(x + (size_t)row * DMq);
        float4 v = xr[tid];
        float ss = v.x*v.x + v.y*v.y + v.z*v.z + v.w*v.w;
        #pragma unroll
        for (int off = 32; off > 0; off >>= 1) ss += __shfl_down(ss, off);
        __shared__ float red[4];
        int lane = tid & 63, wv = tid >> 6;
        if (lane == 0) red[wv] = ss;
        __syncthreads();
        float tot = red[0] + red[1] + red[2] + red[3];
        float rs = rsqrtf(tot * (1.0f / DMq) + EPSf);
        float4 w4 = ((const float4*)ln_w)[tid];
        bf16 t[4] = {f2b(v.x * rs * w4.x), f2b(v.y * rs * w4.y),
                     f2b(v.z * rs * w4.z), f2b(v.w * rs * w4.w)};
        *(uint2*)(xn + (size_t)row * DMq + tid * 4) = *(uint2*)t;
        return;
    }
    const int n1 = QKVW * DMq / 4;               // 786432
    const int n2 = (NPAD - QKVW) * DMq / 4;      // 32768
    const int ng = NGATE * DMq / 4;              // 12288
    const int n3 = DMq * Hq * Dq / 4;            // 262144
    int i = (blockIdx.x - MSc) * 256 + tid;
    if (i < n1) {
        float4 v = ((const float4*)wqkv)[i];
        bf16 t[4] = {f2b(v.x), f2b(v.y), f2b(v.z), f2b(v.w)};
        ((uint2*)wcomb)[i] = *(uint2*)t;
    } else if (i < n1 + n2) {
        int j = i - n1;
        uint2 o = make_uint2(0u, 0u);
        if (j < ng) {
            float4 v = ((const float4*)wgate)[j];
            bf16 t[4] = {f2b(v.x), f2b(v.y), f2b(v.z), f2b(v.w)};
            o = *(uint2*)t;
        }
        ((uint2*)wcomb)[n1 + j] = o;
    } else if (i < n1 + n2 + n3) {
        int j = i - n1 - n2;
        float4 v = ((const float4*)wout)[j];
        bf16 t[4] = {f2b(v.x), f2b(v.y), f2b(v.z), f2b(v.w)};
        ((uint2*)wob)[j] = *(uint2*)t;
    }
}

// ---------------- bf16 MFMA GEMM: LITERAL r4 template (59us / VGPR72 proven) ----------------
// Byte-level revert per rule #19 (co-compiled siblings perturb codegen): template
// dispatch, void* Cv, B-row guard — exactly the r4 source that measured 59us.
enum Epi { EPI_BF16 = 0, EPI_GATE = 1, EPI_RESID = 2 };

template<int EPI>
__global__ __launch_bounds__(256) void gemm_mfma(const bf16* __restrict__ A,
                                                 const bf16* __restrict__ Bw,
                                                 const float* __restrict__ resid,
                                                 void* __restrict__ Cv,
                                                 int M, int N, int K) {
    __shared__ bf16 As[128 * 64];
    __shared__ bf16 Bs[128 * 64];
    const int tid = threadIdx.x;
    const int w = tid >> 6;
    const int l = tid & 63;
    const int wr = (w >> 1) * 64;
    const int wc = (w & 1) * 64;
    const int bm = blockIdx.y * 128;
    const int bn = blockIdx.x * 128;

    const int lrow = l >> 3;
    const int swzc = ((l & 7) ^ lrow) * 8;

    const int fl = l & 15;
    const int kb = l >> 4;
    const int rsw = l & 7;

    f32x4 acc[4][4];
    #pragma unroll
    for (int i = 0; i < 4; i++)
        #pragma unroll
        for (int j = 0; j < 4; j++) acc[i][j] = (f32x4){0.f, 0.f, 0.f, 0.f};

    for (int k0 = 0; k0 < K; k0 += 64) {
        __syncthreads();
        #pragma unroll
        for (int inst = 0; inst < 4; inst++) {
            int r0 = w * 32 + inst * 8;
            const bf16* gp = A + (size_t)(bm + r0 + lrow) * K + k0 + swzc;
            __builtin_amdgcn_global_load_lds(
                (const __attribute__((address_space(1))) uint32_t*)gp,
                (__attribute__((address_space(3))) uint32_t*)(As + r0 * 64),
                16, 0, 0);
        }
        #pragma unroll
        for (int inst = 0; inst < 4; inst++) {
            int r0 = w * 32 + inst * 8;
            if (bn + r0 < N) {
                const bf16* gp = Bw + (size_t)(bn + r0 + lrow) * K + k0 + swzc;
                __builtin_amdgcn_global_load_lds(
                    (const __attribute__((address_space(1))) uint32_t*)gp,
                    (__attribute__((address_space(3))) uint32_t*)(Bs + r0 * 64),
                    16, 0, 0);
            }
        }
        __syncthreads();
        #pragma unroll
        for (int kk2 = 0; kk2 < 2; kk2++) {
            const int koff = (((kk2 << 2) + kb) ^ rsw) * 8;
            short8 af[4], bfr[4];
            #pragma unroll
            for (int i = 0; i < 4; i++)
                af[i] = *(const short8*)(As + (wr + i * 16 + fl) * 64 + koff);
            #pragma unroll
            for (int j = 0; j < 4; j++)
                bfr[j] = *(const short8*)(Bs + (wc + j * 16 + fl) * 64 + koff);
            #pragma unroll
            for (int i = 0; i < 4; i++)
                #pragma unroll
                for (int j = 0; j < 4; j++)
                    acc[i][j] = __builtin_amdgcn_mfma_f32_16x16x32_bf16(
                        af[i], bfr[j], acc[i][j], 0, 0, 0);
        }
    }

    #pragma unroll
    for (int i = 0; i < 4; i++) {
        #pragma unroll
        for (int j = 0; j < 4; j++) {
            int col = bn + wc + j * 16 + fl;
            if (EPI == EPI_GATE && col >= N) continue;
            #pragma unroll
            for (int r = 0; r < 4; r++) {
                int row = bm + wr + i * 16 + kb * 4 + r;
                size_t idx = (size_t)row * N + col;
                float v = acc[i][j][r];
                if (EPI == EPI_GATE) {
                    ((float*)Cv)[idx] = gate_act(v);
                } else if (EPI == EPI_RESID) {
                    ((float*)Cv)[idx] = v + resid[idx];
                } else {
                    ((bf16*)Cv)[idx] = f2b(v);
                }
            }
        }
    }
}
// mirror r4's co-compilation context: all three instantiations present
template __global__ void gemm_mfma<EPI_BF16>(const bf16*, const bf16*, const float*, void*, int, int, int);
template __global__ void gemm_mfma<EPI_GATE>(const bf16*, const bf16*, const float*, void*, int, int, int);
template __global__ void gemm_mfma<EPI_RESID>(const bf16*, const bf16*, const float*, void*, int, int, int);

// ---------------- skinny gates GEMM: 32 rows x 48 cols per block, 1 wave ----------------
__global__ __launch_bounds__(64) void gemm_gates(const bf16* __restrict__ A,
                                                 const bf16* __restrict__ Bw,
                                                 float* __restrict__ gates_t,
                                                 int M, int K) {
    const int bm = blockIdx.x * 32;
    const int l = threadIdx.x, fl = l & 15, kb = l >> 4;
    f32x4 acc[2][3];
    #pragma unroll
    for (int i = 0; i < 2; i++)
        #pragma unroll
        for (int j = 0; j < 3; j++) acc[i][j] = (f32x4){0.f, 0.f, 0.f, 0.f};

    for (int ks = 0; ks < K; ks += 32) {
        short8 af[2], bf[3];
        #pragma unroll
        for (int i = 0; i < 2; i++)
            af[i] = *(const short8*)(A + (size_t)(bm + i * 16 + fl) * K + ks + kb * 8);
        #pragma unroll
        for (int j = 0; j < 3; j++)
            bf[j] = *(const short8*)(Bw + (size_t)(j * 16 + fl) * K + ks + kb * 8);
        #pragma unroll
        for (int i = 0; i < 2; i++)
            #pragma unroll
            for (int j = 0; j < 3; j++)
                acc[i][j] = __builtin_amdgcn_mfma_f32_16x16x32_bf16(af[i], bf[j], acc[i][j], 0, 0, 0);
    }
    #pragma unroll
    for (int i = 0; i < 2; i++)
        #pragma unroll
        for (int j = 0; j < 3; j++)
            #pragma unroll
            for (int r = 0; r < 4; r++) {
                int row = bm + i * 16 + kb * 4 + r;
                int g = j * 16 + fl;
                gates_t[(size_t)g * M + row] = gate_act(acc[i][j][r]);
            }
}

// ---------------- chunk kernel A: intra-chunk attention + chunk state ----------------
// LDS reduced 24.75->16.75 KiB: Ps reuses the KTs buffer (accL consumes KTs
// before Ps is written; single-wave block -> barriers are free, no race).
// Occupancy 6 -> 9 blocks/CU.
__global__ __launch_bounds__(64) void chunk_intra(const bf16* __restrict__ qkvb,
                                                  const float* __restrict__ gates,
                                                  bf16* __restrict__ attb,
                                                  bf16* __restrict__ LT,
                                                  float* __restrict__ oaArr,
                                                  float* __restrict__ Fch) {
    const int blk = blockIdx.x;
    const int c  = blk & (Cc - 1);
    const int bh = blk >> 5;
    const int b = bh >> 4, hh = bh & 15;
    const int l = threadIdx.x;
    const int s0 = c * Tc;

    __shared__ bf16 KTs[4096];   // reused as Ps after accL
    __shared__ bf16 VTs[4096];
    __shared__ float rowS[64], pcolS[64], wstS[64];

    // gates in [48][MS] layout -> coalesced 64-lane reads
    const int rix = b * Sq + s0 + l;
    float ig = gates[(size_t)(0 * Hq + hh) * MSc + rix];
    float fg = gates[(size_t)(1 * Hq + hh) * MSc + rix];
    float og = gates[(size_t)(2 * Hq + hh) * MSc + rix];
    float la = __logf(fg);
    #pragma unroll
    for (int off = 1; off < 64; off <<= 1) {
        float v = __shfl_up(la, off);
        if (l >= off) la += v;
    }
    float la63 = __shfl(la, 63);
    float li = __logf(ig);
    rowS[l]  = la + __logf(og);
    pcolS[l] = li - la;
    wstS[l]  = __expf(la63 - la + li);
    float oa = og * __expf(la);
    oaArr[(size_t)blk * 64 + l] = oa;
    if (l == 0) Fch[blk] = __expf(la63);
    __syncthreads();

    const int cg = l & 7, rp = l >> 3;
    const size_t rowBase = (size_t)(b * Sq + s0);
    const int kcol = (Hq + hh) * Dq, vcol = (2 * Hq + hh) * Dq;
    #pragma unroll
    for (int pass = 0; pass < 4; pass++) {
        int j0 = pass * 16 + rp * 2;
        const bf16* r0 = qkvb + (rowBase + j0) * QKVW;
        const bf16* r1 = qkvb + (rowBase + j0 + 1) * QKVW;
        short8 k0 = *(const short8*)(r0 + kcol + cg * 8);
        short8 k1 = *(const short8*)(r1 + kcol + cg * 8);
        short8 v0 = *(const short8*)(r0 + vcol + cg * 8);
        short8 v1 = *(const short8*)(r1 + vcol + cg * 8);
        float w0 = wstS[j0], w1 = wstS[j0 + 1];
        #pragma unroll
        for (int s = 0; s < 8; s++) {
            int cc = cg * 8 + s;
            int base = cc * 64 + ((((j0 >> 3) ^ (cc & 7) ^ (cc >> 3))) << 3) + (j0 & 7);
            uint32_t kp = (uint32_t)f2bu(bu2f((uint16_t)k0[s]) * w0)
                        | ((uint32_t)f2bu(bu2f((uint16_t)k1[s]) * w1) << 16);
            uint32_t vp = (uint32_t)(uint16_t)v0[s] | ((uint32_t)(uint16_t)v1[s] << 16);
            *(uint32_t*)&KTs[base] = kp;
            *(uint32_t*)&VTs[base] = vp;
        }
    }
    __syncthreads();

    const int fl = l & 15, kb = l >> 4;

    // accL = VT @ KT^T first (so KTs can be reused for Ps)
    f32x4 accL[4][4];
    #pragma unroll
    for (int i = 0; i < 4; i++)
        #pragma unroll
        for (int j = 0; j < 4; j++) accL[i][j] = (f32x4){0.f, 0.f, 0.f, 0.f};
    #pragma unroll
    for (int ks = 0; ks < 2; ks++) {
        short8 vt[4], kt[4];
        #pragma unroll
        for (int i = 0; i < 4; i++) {
            int row = i * 16 + fl;
            int koff = (((ks * 4 + kb) ^ (row & 7) ^ (row >> 3))) << 3;
            vt[i] = *(const short8*)(VTs + row * 64 + koff);
            kt[i] = *(const short8*)(KTs + row * 64 + koff);
        }
        #pragma unroll
        for (int i = 0; i < 4; i++)
            #pragma unroll
            for (int j = 0; j < 4; j++)
                accL[i][j] = __builtin_amdgcn_mfma_f32_16x16x32_bf16(vt[i], kt[j], accL[i][j], 0, 0, 0);
    }
    #pragma unroll
    for (int i = 0; i < 4; i++)
        #pragma unroll
        for (int j = 0; j < 4; j++)
            #pragma unroll
            for (int r = 0; r < 4; r++) {
                int rr = i * 16 + kb * 4 + r, cc2 = j * 16 + fl;
                LT[(size_t)blk * 4096 + rr * 64 + cc2] = f2b(accL[i][j][r]);
            }

    // S = Q @ K^T from direct global frag loads
    const bf16* Qb = qkvb + rowBase * QKVW + hh * Dq;
    const bf16* Kb = qkvb + rowBase * QKVW + kcol;
    f32x4 accS[4][4];
    #pragma unroll
    for (int i = 0; i < 4; i++)
        #pragma unroll
        for (int j = 0; j < 4; j++) accS[i][j] = (f32x4){0.f, 0.f, 0.f, 0.f};
    #pragma unroll
    for (int ks = 0; ks < 2; ks++) {
        short8 qf[4], kf[4];
        #pragma unroll
        for (int i = 0; i < 4; i++)
            qf[i] = *(const short8*)(Qb + (size_t)(i * 16 + fl) * QKVW + ks * 32 + kb * 8);
        #pragma unroll
        for (int j = 0; j < 4; j++)
            kf[j] = *(const short8*)(Kb + (size_t)(j * 16 + fl) * QKVW + ks * 32 + kb * 8);
        #pragma unroll
        for (int i = 0; i < 4; i++)
            #pragma unroll
            for (int j = 0; j < 4; j++)
                accS[i][j] = __builtin_amdgcn_mfma_f32_16x16x32_bf16(qf[i], kf[j], accS[i][j], 0, 0, 0);
    }

    __syncthreads();   // all accL reads of KTs complete (1-wave: free)
    bf16* Ps = KTs;    // reuse buffer
    #pragma unroll
    for (int i = 0; i < 4; i++) {
        #pragma unroll
        for (int j = 0; j < 4; j++) {
            int jj = j * 16 + fl;
            float pc = pcolS[jj];
            #pragma unroll
            for (int r = 0; r < 4; r++) {
                int t = i * 16 + kb * 4 + r;
                float p = (jj <= t) ? __expf(rowS[t] + pc) * accS[i][j][r] : 0.f;
                int slot = (jj >> 3) ^ (t & 7) ^ (t >> 3);
                Ps[t * 64 + slot * 8 + (jj & 7)] = f2b(p);
            }
        }
    }
    __syncthreads();

    // out = P @ V
    f32x4 accO[4][4];
    #pragma unroll
    for (int i = 0; i < 4; i++)
        #pragma unroll
        for (int j = 0; j < 4; j++) accO[i][j] = (f32x4){0.f, 0.f, 0.f, 0.f};
    #pragma unroll
    for (int ks = 0; ks < 2; ks++) {
        short8 pf[4], vt[4];
        #pragma unroll
        for (int i = 0; i < 4; i++) {
            int row = i * 16 + fl;
            int koff = (((ks * 4 + kb) ^ (row & 7) ^ (row >> 3))) << 3;
            pf[i] = *(const short8*)(Ps  + row * 64 + koff);
            vt[i] = *(const short8*)(VTs + row * 64 + koff);
        }
        #pragma unroll
        for (int i = 0; i < 4; i++)
            #pragma unroll
            for (int j = 0; j < 4; j++)
                accO[i][j] = __builtin_amdgcn_mfma_f32_16x16x32_bf16(pf[i], vt[j], accO[i][j], 0, 0, 0);
    }

    #pragma unroll
    for (int i = 0; i < 4; i++)
        #pragma unroll
        for (int j = 0; j < 4; j++)
            #pragma unroll
            for (int r = 0; r < 4; r++) {
                int rr = i * 16 + kb * 4 + r, cc2 = j * 16 + fl;
                attb[(rowBase + rr) * (Hq * Dq) + hh * Dq + cc2] = f2b(accO[i][j][r]);
            }
}

// ---------------- pass2: cross-chunk combine ----------------
__global__ __launch_bounds__(256) void scan_pass2(bf16* __restrict__ LH,
                                                  const float* __restrict__ Fchunk,
                                                  const float* __restrict__ h0,
                                                  float* __restrict__ hfin) {
    int idx = blockIdx.x * 256 + threadIdx.x;
    int bh = idx >> 12;
    int ed = idx & 4095;
    int e = ed >> 6, d = ed & 63;
    float run = h0[(size_t)bh * 4096 + d * 64 + e];
    #pragma unroll
    for (int c = 0; c < Cc; c++) {
        float Fv = Fchunk[bh * Cc + c];
        size_t off = ((size_t)bh * Cc + c) * 4096 + ed;
        float Lv = b2f(LH[off]);
        LH[off] = f2b(run);
        run = Fv * run + Lv;
    }
    hfin[(size_t)bh * 4096 + d * 64 + e] = run;
}

// ---------------- chunk kernel B: cross-chunk contribution ----------------
__global__ __launch_bounds__(64) void chunk_cross(const bf16* __restrict__ qkvb,
                                                  const bf16* __restrict__ HT,
                                                  const float* __restrict__ oaArr,
                                                  bf16* __restrict__ attb) {
    const int blk = blockIdx.x;
    const int c = blk & (Cc - 1);
    const int bh = blk >> 5;
    const int b = bh >> 4, hh = bh & 15;
    const int l = threadIdx.x, fl = l & 15, kb = l >> 4;
    const size_t rowBase = (size_t)(b * Sq + c * Tc);
    __shared__ float oaS[64];
    oaS[l] = oaArr[(size_t)blk * 64 + l];
    __syncthreads();
    const bf16* Qb = qkvb + rowBase * QKVW + hh * Dq;
    const bf16* Hb = HT + (size_t)blk * 4096;
    f32x4 acc[4][4];
    #pragma unroll
    for (int i = 0; i < 4; i++)
        #pragma unroll
        for (int j = 0; j < 4; j++) acc[i][j] = (f32x4){0.f, 0.f, 0.f, 0.f};
    #pragma unroll
    for (int ks = 0; ks < 2; ks++) {
        short8 qf[4], hf[4];
        #pragma unroll
        for (int i = 0; i < 4; i++)
            qf[i] = *(const short8*)(Qb + (size_t)(i * 16 + fl) * QKVW + ks * 32 + kb * 8);
        #pragma unroll
        for (int j = 0; j < 4; j++)
            hf[j] = *(const short8*)(Hb + (j * 16 + fl) * 64 + ks * 32 + kb * 8);
        #pragma unroll
        for (int i = 0; i < 4; i++)
            #pragma unroll
            for (int j = 0; j < 4; j++)
                acc[i][j] = __builtin_amdgcn_mfma_f32_16x16x32_bf16(qf[i], hf[j], acc[i][j], 0, 0, 0);
    }
    #pragma unroll
    for (int i = 0; i < 4; i++)
        #pragma unroll
        for (int j = 0; j < 4; j++)
            #pragma unroll
            for (int r = 0; r < 4; r++) {
                int t = i * 16 + kb * 4 + r, e = j * 16 + fl;
                size_t idx = (rowBase + t) * (Hq * Dq) + hh * Dq + e;
                attb[idx] = f2b(b2f(attb[idx]) + oaS[t] * acc[i][j][r]);
            }
}

extern "C" void kernel_launch(void* const* d_in, const int* in_sizes, int n_in,
                              void* d_out, int out_size, void* d_ws, size_t ws_size,
                              hipStream_t stream) {
    const float* x      = (const float*)d_in[0];
    const float* h0     = (const float*)d_in[1];
    const float* w_qkv  = (const float*)d_in[2];
    const float* w_gate = (const float*)d_in[3];
    const float* w_out  = (const float*)d_in[4];
    const float* ln_w   = (const float*)d_in[5];

    const size_t MS = (size_t)Bq * Sq;            // 8192
    const size_t BH = (size_t)Bq * Hq;            // 64

    float* p = (float*)d_ws;
    bf16*  xnb   = (bf16*)p;  p += MS * DMq / 2;
    bf16*  qkvb  = (bf16*)p;  p += MS * QKVW / 2;
    float* gates = p;         p += MS * NGATE;            // layout [48][MS]
    float* oaArr = p;         p += BH * Cc * Tc;
    float* Fch   = p;         p += BH * Cc;
    bf16*  LT    = (bf16*)p;  p += BH * Cc * Dq * Dq / 2;
    bf16*  wcomb = (bf16*)p;  p += (size_t)NPAD * DMq / 2;
    bf16*  wob   = (bf16*)p;  p += (size_t)DMq * Hq * Dq / 2;
    size_t need = (size_t)(p - (float*)d_ws) * sizeof(float);
    if (ws_size < need) return;
    bf16* attb = xnb;   // alias: xnb dead after QKV+gates GEMMs

    float* y    = (float*)d_out;
    float* hfin = y + MS * DMq;

    const int cvt_n = (QKVW * DMq + (NPAD - QKVW) * DMq + DMq * Hq * Dq) / 4;
    const int cvt_blocks = (cvt_n + 255) / 256;
    prep_kernel<<<dim3(MS + cvt_blocks), dim3(256), 0, stream>>>(
        x, ln_w, w_qkv, w_gate, w_out, xnb, wcomb, wob);

    gemm_mfma<EPI_BF16><<<dim3(QKVW / 128, MS / 128), dim3(256), 0, stream>>>(
        xnb, wcomb, nullptr, qkvb, (int)MS, QKVW, DMq);

    gemm_gates<<<dim3(MS / 32), dim3(64), 0, stream>>>(
        xnb, wcomb + (size_t)QKVW * DMq, gates, (int)MS, DMq);

    chunk_intra<<<dim3(BH * Cc), dim3(64), 0, stream>>>(qkvb, gates, attb, LT, oaArr, Fch);
    scan_pass2<<<dim3(BH * 4096 / 256), dim3(256), 0, stream>>>(LT, Fch, h0, hfin);
    chunk_cross<<<dim3(BH * Cc), dim3(64), 0, stream>>>(qkvb, LT, oaArr, attb);

    gemm_mfma<EPI_RESID><<<dim3(DMq / 128, MS / 128), dim3(256), 0, stream>>>(
        attb, wob, x, y, (int)MS, DMq, Hq * Dq);
}